// Round 13
// baseline (1647.680 us; speedup 1.0000x reference)
//
#include <hip/hip_runtime.h>
#include <cstddef>

namespace {

constexpr int T = 128;

typedef unsigned short u16;
typedef unsigned int u32;
typedef __attribute__((ext_vector_type(8))) short short8;
typedef __attribute__((ext_vector_type(4))) float f32x4;
typedef __attribute__((ext_vector_type(4))) int i32x4;

__device__ __forceinline__ u16 f2bf(float x) {
  u32 u = __float_as_uint(x);
  u = (u + 0x7FFFu + ((u >> 16) & 1u)) >> 16;
  return (u16)u;
}
__device__ __forceinline__ float bf2f(u16 v) {
  return __uint_as_float(((u32)v) << 16);
}
// exp2/rcp-based activations: single v_exp_f32 / v_rcp_f32, branch-free.
__device__ __forceinline__ float sigf(float x) {
  return __builtin_amdgcn_rcpf(1.f + __builtin_amdgcn_exp2f(-1.44269504f * x));
}
__device__ __forceinline__ float tanh2(float x) {
  return 1.f - 2.f * __builtin_amdgcn_rcpf(1.f + __builtin_amdgcn_exp2f(2.88539008f * x));
}
// Barrier that drains ONLY LDS ops (lgkmcnt) — __syncthreads would also wait
// vmcnt(0), serializing on HBM store-acks that nothing after depends on.
__device__ __forceinline__ void bar_lds() {
  asm volatile("s_waitcnt lgkmcnt(0)\n\ts_barrier" ::: "memory");
}

// ---- WBF sub-offsets (ushort units) ----
constexpr int O_WIH = 0;            // 2*2048*512
constexpr int O_AW1 = 2097152;      // 512*512
constexpr int O_EM1 = 2359296;      // 128*128
constexpr int O_EM2 = 2375680;      // 64*128
constexpr int O_MLP = 2383872;      // 64*512
constexpr int O_LW1 = 2416640;      // 256*128
constexpr int O_LW2 = 2449408;      // 128*256
constexpr int O_LW3 = 2482176;      // 64*128
constexpr int N_WBF = 2490368;

// ---------------------------------------------------------------------------
// One-time fp32 -> bf16 weight conversion into workspace
// ---------------------------------------------------------------------------
__global__ __launch_bounds__(256)
void k_prep(const float* __restrict__ wih, const float* __restrict__ aw1,
            const float* __restrict__ e1, const float* __restrict__ e2,
            const float* __restrict__ mw, const float* __restrict__ l1,
            const float* __restrict__ l2, const float* __restrict__ l3,
            u16* __restrict__ wbf) {
  int i = blockIdx.x * 256 + threadIdx.x;
  if (i >= N_WBF) return;
  float v;
  if (i < O_AW1)      v = wih[i];
  else if (i < O_EM1) v = aw1[i - O_AW1];
  else if (i < O_EM2) v = e1[i - O_EM1];
  else if (i < O_MLP) v = e2[i - O_EM2];
  else if (i < O_LW1) v = mw[i - O_MLP];
  else if (i < O_LW2) v = l1[i - O_LW1];
  else if (i < O_LW3) v = l2[i - O_LW2];
  else                v = l3[i - O_LW3];
  wbf[i] = f2bf(v);
}

// ---------------------------------------------------------------------------
// Whh fp32 -> i8 (scale 1016 = 127/0.125; |w|max ~0.097, no clipping)
// ---------------------------------------------------------------------------
__global__ __launch_bounds__(256)
void k_prepw(const float* __restrict__ whh, signed char* __restrict__ wq) {
  int i = blockIdx.x * 256 + threadIdx.x;   // 1,048,576 total
  float v = whh[i] * 1016.f;
  v = fminf(fmaxf(v, -127.f), 127.f);
  wq[i] = (signed char)(int)rintf(v);
}

// ---------------------------------------------------------------------------
// xg = X @ Wih_l^T + bih + bhh   via MFMA.  grid (256 rowblk, 8 nchunk)
// ---------------------------------------------------------------------------
__global__ __launch_bounds__(256)
void k_xg_mfma(const float* __restrict__ X, const u16* __restrict__ Wbf,
               const float* __restrict__ bi, const float* __restrict__ bh,
               float* __restrict__ xg) {
  __shared__ __align__(16) u16 sx[32 * 520];
  int tid = threadIdx.x;
  int rowbase = blockIdx.x * 32;
  int nchunk = blockIdx.y;
  for (int idx = tid; idx < 4096; idx += 256) {
    int r = idx >> 7, k4 = idx & 127;
    float4 v = *(const float4*)(X + (size_t)(rowbase + r) * 512 + k4 * 4);
    u32* p = (u32*)(sx + r * 520 + k4 * 4);
    p[0] = (u32)f2bf(v.x) | ((u32)f2bf(v.y) << 16);
    p[1] = (u32)f2bf(v.z) | ((u32)f2bf(v.w) << 16);
  }
  __syncthreads();
  int w = tid >> 6, lane = tid & 63;
  int msub = w >> 1, nhalf = w & 1;
  int mbase = msub * 16;
  int nb0 = nchunk * 256 + nhalf * 128;
  f32x4 acc[8];
#pragma unroll
  for (int i = 0; i < 8; ++i) acc[i] = f32x4{0.f, 0.f, 0.f, 0.f};
  for (int kt = 0; kt < 16; ++kt) {
    short8 a = *(const short8*)(sx + (mbase + (lane & 15)) * 520 + kt * 32 + (lane >> 4) * 8);
#pragma unroll
    for (int nt = 0; nt < 8; ++nt) {
      short8 b = *(const short8*)(Wbf + (size_t)(nb0 + nt * 16 + (lane & 15)) * 512 +
                                  kt * 32 + (lane >> 4) * 8);
      acc[nt] = __builtin_amdgcn_mfma_f32_16x16x32_bf16(a, b, acc[nt], 0, 0, 0);
    }
  }
  int mr = mbase + (lane >> 4) * 4;
#pragma unroll
  for (int nt = 0; nt < 8; ++nt) {
    int n = nb0 + nt * 16 + (lane & 15);
    float bb = bi[n] + bh[n];
#pragma unroll
    for (int r = 0; r < 4; ++r)
      xg[(size_t)(rowbase + mr + r) * 2048 + n] = acc[nt][r] + bb;
  }
}

// ---------------------------------------------------------------------------
// MFMA LSTM v9: batch-split, ZERO inter-block sync. 8 blocks = [d:2][bg:4],
// 1024 threads (16 waves = 4 waves/SIMD for latency hiding). Each wave owns
// 16 j-cols; Bq = 16 i32x4 = 64 VGPR. h in block-local LDS, one lgkm barrier
// per step. xv loaded at step top (r11-proven schedule).
// ---------------------------------------------------------------------------
__global__ __launch_bounds__(1024, 1)
void k_lstm6(const float* __restrict__ xg, const signed char* __restrict__ wq,
             const int* __restrict__ lens, float* __restrict__ out, int layer) {
  __shared__ __align__(16) signed char hq[2][16 * 272];
  const int d = blockIdx.x >> 2, bg = blockIdx.x & 3;
  const int tid = threadIdx.x;
  const int jc = tid >> 6, l = tid & 63, ln = l & 15, lk = l >> 4;
  const int mb = bg * 16;
  const int j = jc * 16 + ln;          // this lane's hidden col [0,256)

  // ---- weights: 16 B-frags (4 g x 4 kc) = 64 VGPR ----
  i32x4 Bq[4][4];
  const signed char* wbase = wq + (size_t)(layer * 2 + d) * 262144;
#pragma unroll
  for (int g = 0; g < 4; ++g)
#pragma unroll
    for (int kc = 0; kc < 4; ++kc) {
      int n = g * 256 + j;
      Bq[g][kc] = *(const i32x4*)(wbase + (size_t)n * 256 + kc * 64 + lk * 16);
    }

  int mlen[4];
#pragma unroll
  for (int r = 0; r < 4; ++r) mlen[r] = lens[mb + lk * 4 + r];

  float cst[4], hst[4];
#pragma unroll
  for (int r = 0; r < 4; ++r) { cst[r] = 0.f; hst[r] = 0.f; }

  const float DEQ = 1.f / (1016.f * 127.f);

  for (int s = 0; s < 128; ++s) {
    const int t = d ? (127 - s) : s;

    // xg pre-activations: issued first, consumed at gates (after MFMA)
    float xv[4][4];
#pragma unroll
    for (int g = 0; g < 4; ++g)
#pragma unroll
      for (int r = 0; r < 4; ++r)
        xv[g][r] = xg[((size_t)(mb + lk * 4 + r) * 128 + t) * 2048 +
                      d * 1024 + g * 256 + j];

    i32x4 acc[4];
#pragma unroll
    for (int g = 0; g < 4; ++g) acc[g] = i32x4{0, 0, 0, 0};

    if (s > 0) {
      const signed char* hr = hq[(s & 1) ^ 1];
#pragma unroll
      for (int kc = 0; kc < 4; ++kc) {
        i32x4 a = *(const i32x4*)(hr + ln * 272 + kc * 64 + lk * 16);
#pragma unroll
        for (int g = 0; g < 4; ++g)
          acc[g] = __builtin_amdgcn_mfma_i32_16x16x64_i8(a, Bq[g][kc], acc[g], 0, 0, 0);
      }
    }

    signed char* hw = hq[s & 1];
#pragma unroll
    for (int r = 0; r < 4; ++r) {
      float gi = (float)acc[0][r] * DEQ + xv[0][r];
      float gf = (float)acc[1][r] * DEQ + xv[1][r];
      float gg = (float)acc[2][r] * DEQ + xv[2][r];
      float go = (float)acc[3][r] * DEQ + xv[3][r];
      float c2 = sigf(gf) * cst[r] + sigf(gi) * tanh2(gg);
      float h2 = sigf(go) * tanh2(c2);
      const int m = lk * 4 + r;
      bool upd = t < mlen[r];
      cst[r] = upd ? c2 : cst[r];
      float hn = upd ? h2 : hst[r];
      hst[r] = hn;
      out[((size_t)(mb + m) * 128 + t) * 512 + d * 256 + j] = hn;
      hw[m * 272 + j] = (signed char)(int)rintf(hn * 127.f);
    }
    bar_lds();
  }
}

// ---------------------------------------------------------------------------
// attn scores via MFMA: sc[m] = w2 . tanh(W1 @ rnn[m] + b1)
// ---------------------------------------------------------------------------
__global__ __launch_bounds__(256)
void k_attn(const float* __restrict__ rnn, const u16* __restrict__ W1bf,
            const float* __restrict__ b1, const float* __restrict__ w2,
            float* __restrict__ sc) {
  __shared__ __align__(16) u16 sx[32 * 520];
  __shared__ float sred[32];
  int tid = threadIdx.x;
  int rowbase = blockIdx.x * 32;
  for (int idx = tid; idx < 4096; idx += 256) {
    int r = idx >> 7, k4 = idx & 127;
    float4 v = *(const float4*)(rnn + (size_t)(rowbase + r) * 512 + k4 * 4);
    u32* p = (u32*)(sx + r * 520 + k4 * 4);
    p[0] = (u32)f2bf(v.x) | ((u32)f2bf(v.y) << 16);
    p[1] = (u32)f2bf(v.z) | ((u32)f2bf(v.w) << 16);
  }
  if (tid < 32) sred[tid] = 0.f;
  __syncthreads();
  int w = tid >> 6, lane = tid & 63;
  int msub = w >> 1, nhalf = w & 1;
  int mbase = msub * 16;
  float psum[4] = {0.f, 0.f, 0.f, 0.f};
  for (int ng = 0; ng < 4; ++ng) {
    f32x4 acc[4];
#pragma unroll
    for (int i = 0; i < 4; ++i) acc[i] = f32x4{0.f, 0.f, 0.f, 0.f};
    for (int kt = 0; kt < 16; ++kt) {
      short8 a = *(const short8*)(sx + (mbase + (lane & 15)) * 520 + kt * 32 + (lane >> 4) * 8);
#pragma unroll
      for (int nt = 0; nt < 4; ++nt) {
        int nrow = nhalf * 256 + ng * 64 + nt * 16 + (lane & 15);
        short8 b = *(const short8*)(W1bf + (size_t)nrow * 512 + kt * 32 + (lane >> 4) * 8);
        acc[nt] = __builtin_amdgcn_mfma_f32_16x16x32_bf16(a, b, acc[nt], 0, 0, 0);
      }
    }
#pragma unroll
    for (int nt = 0; nt < 4; ++nt) {
      int n = nhalf * 256 + ng * 64 + nt * 16 + (lane & 15);
      float wn = w2[n], bn = b1[n];
#pragma unroll
      for (int r = 0; r < 4; ++r) psum[r] += wn * tanh2(acc[nt][r] + bn);
    }
  }
#pragma unroll
  for (int off = 8; off >= 1; off >>= 1)
#pragma unroll
    for (int r = 0; r < 4; ++r) psum[r] += __shfl_xor(psum[r], off);
  if ((lane & 15) == 0) {
#pragma unroll
    for (int r = 0; r < 4; ++r)
      atomicAdd(&sred[msub * 16 + (lane >> 4) * 4 + r], psum[r]);
  }
  __syncthreads();
  if (tid < 32) sc[rowbase + tid] = sred[tid];
}

// ---------------------------------------------------------------------------
// Causal softmax + weighted sum as prefix scan. grid (64 b, 4 hchunk) x 128.
// ---------------------------------------------------------------------------
__global__ __launch_bounds__(128)
void k_ctx(const float* __restrict__ sc, const float* __restrict__ rnn,
           const int* __restrict__ lens, float* __restrict__ ctx) {
  int b = blockIdx.x;
  int h = blockIdx.y * 128 + threadIdx.x;
  __shared__ float ex[T];
  ex[threadIdx.x] = expf(sc[b * T + threadIdx.x]);
  __syncthreads();
  int len = lens[b];
  float acc = 0.f, den = 0.f;
  for (int t = 0; t < T; ++t) {
    float wv = ex[t];
    den += wv;
    acc += wv * rnn[((size_t)b * T + t) * 512 + h];
    ctx[((size_t)b * T + t) * 512 + h] = (t < len) ? (acc / den) : 0.f;
  }
}

// ---------------------------------------------------------------------------
// MFMA MLP stage on a 32-row bf16 LDS tile
// ---------------------------------------------------------------------------
template <int NT, int KT, bool RELU>
__device__ __forceinline__ void stage_mfma(const u16* __restrict__ Wbf,
                                           const float* __restrict__ bias,
                                           const u16* A, int lda,
                                           u16* O, int ldo, int nofs,
                                           int lane, int msub, int nhalf) {
  f32x4 acc[NT];
#pragma unroll
  for (int i = 0; i < NT; ++i) acc[i] = f32x4{0.f, 0.f, 0.f, 0.f};
  int mbase = msub * 16;
  int nb0 = nhalf * (NT * 16);
#pragma unroll
  for (int kt = 0; kt < KT; ++kt) {
    short8 a = *(const short8*)(A + (mbase + (lane & 15)) * lda + kt * 32 + (lane >> 4) * 8);
#pragma unroll
    for (int nt = 0; nt < NT; ++nt) {
      short8 b = *(const short8*)(Wbf + (size_t)(nb0 + nt * 16 + (lane & 15)) * (KT * 32) +
                                  kt * 32 + (lane >> 4) * 8);
      acc[nt] = __builtin_amdgcn_mfma_f32_16x16x32_bf16(a, b, acc[nt], 0, 0, 0);
    }
  }
  int mr = mbase + (lane >> 4) * 4;
#pragma unroll
  for (int nt = 0; nt < NT; ++nt) {
    int nl = nb0 + nt * 16 + (lane & 15);
    float bv = bias[nl];
#pragma unroll
    for (int r = 0; r < 4; ++r) {
      float v = acc[nt][r] + bv;
      if (RELU) v = fmaxf(v, 0.f);
      O[(mr + r) * ldo + nofs + nl] = f2bf(v);
    }
  }
}

// ---------------------------------------------------------------------------
// Fused sample branch. 32 rows/block, 4096 blocks, LDS 42.6 KB (3 blk/CU).
// ALL HBM gathers (user/art/d2v) issued into registers at kernel top so
// their latency hides under the MFMA stage chain.
// ---------------------------------------------------------------------------
__global__ __launch_bounds__(256)
void k_sample(const float* __restrict__ ctx, const float* __restrict__ d2v,
              const float* __restrict__ user_table, const float* __restrict__ art_table,
              const int* __restrict__ user_ids, const int* __restrict__ sample_ids,
              const u16* __restrict__ wbf,
              const float* __restrict__ em_b1, const float* __restrict__ em_b2,
              const float* __restrict__ mlp_b,
              const float* __restrict__ lm_b1, const float* __restrict__ lm_b2,
              const float* __restrict__ lm_b3,
              const float* __restrict__ lm_W4, const float* __restrict__ lm_b4,
              float* __restrict__ out) {
  __shared__ __align__(16) u16 bufA[32 * 264];
  __shared__ __align__(16) u16 bufB[32 * 264];
  __shared__ __align__(16) u16 bufC[32 * 136];
  __shared__ float sred[32];
  int tid = threadIdx.x, lane = tid & 63, w = tid >> 6;
  int msub = w >> 1, nhalf = w & 1;
  int mbase = msub * 16;
  int rowbase = blockIdx.x * 32;

  if (tid < 32) sred[tid] = 0.f;

  // ---- phase 0: issue ALL HBM gathers into registers ----
  float4 uu[4], aa[4];
#pragma unroll
  for (int it = 0; it < 4; ++it) {
    int idx = it * 256 + tid;
    int r = idx >> 5, k4 = idx & 31;
    int m = rowbase + r;
    int sid = sample_ids[m];
    int uid = user_ids[m >> 11];
    uu[it] = *(const float4*)(user_table + (size_t)uid * 128 + k4 * 4);
    aa[it] = *(const float4*)(art_table + (size_t)sid * 128 + k4 * 4);
  }
  float4 dd0[8];
#pragma unroll
  for (int it = 0; it < 8; ++it) {
    int idx = it * 256 + tid;
    int r = idx >> 6, k4 = idx & 63;
    int m = rowbase + r;
    dd0[it] = *(const float4*)(d2v + (size_t)m * 512 + k4 * 4);
  }

  // e0 = user_emb * art_emb  -> bufA[:, 0:128]   (pure register repack)
#pragma unroll
  for (int it = 0; it < 4; ++it) {
    int idx = it * 256 + tid;
    int r = idx >> 5, k4 = idx & 31;
    float4 u = uu[it], a = aa[it];
    u32* p = (u32*)(bufA + r * 264 + k4 * 4);
    p[0] = (u32)f2bf(u.x * a.x) | ((u32)f2bf(u.y * a.y) << 16);
    p[1] = (u32)f2bf(u.z * a.z) | ((u32)f2bf(u.w * a.w) << 16);
  }
  bar_lds();
  stage_mfma<4, 4, true>(wbf + O_EM1, em_b1, bufA, 264, bufB, 264, 0, lane, msub, nhalf);
  bar_lds();
  // em2 (bufB->bufC) + d2v chunk1 issue + r-chunk0 staging share this region
  stage_mfma<2, 4, true>(wbf + O_EM2, em_b2, bufB, 264, bufC, 136, 0, lane, msub, nhalf);
  float4 dd1[8];
#pragma unroll
  for (int it = 0; it < 8; ++it) {
    int idx = it * 256 + tid;
    int r = idx >> 6, k4 = idx & 63;
    int m = rowbase + r;
    dd1[it] = *(const float4*)(d2v + (size_t)m * 512 + 256 + k4 * 4);
  }
#pragma unroll
  for (int it = 0; it < 8; ++it) {
    int idx = it * 256 + tid;
    int r = idx >> 6, k4 = idx & 63;
    int m = rowbase + r;
    int bt = m >> 4;
    float4 cx = *(const float4*)(ctx + (size_t)bt * 512 + k4 * 4);
    float4 dv = dd0[it];
    u32* p = (u32*)(bufA + r * 264 + k4 * 4);
    p[0] = (u32)f2bf(cx.x * dv.x) | ((u32)f2bf(cx.y * dv.y) << 16);
    p[1] = (u32)f2bf(cx.z * dv.z) | ((u32)f2bf(cx.w * dv.w) << 16);
  }
  bar_lds();

  // r = (ctx*d2v) @ mlp_W^T : accumulate over 2 K-chunks of 256
  f32x4 racc[2];
  racc[0] = f32x4{0.f, 0.f, 0.f, 0.f};
  racc[1] = f32x4{0.f, 0.f, 0.f, 0.f};
  for (int kc = 0; kc < 2; ++kc) {
#pragma unroll
    for (int kt = 0; kt < 8; ++kt) {
      short8 a = *(const short8*)(bufA + (mbase + (lane & 15)) * 264 + kt * 32 + (lane >> 4) * 8);
#pragma unroll
      for (int nt = 0; nt < 2; ++nt) {
        int n = nhalf * 32 + nt * 16 + (lane & 15);
        short8 b = *(const short8*)(wbf + O_MLP + (size_t)n * 512 + kc * 256 +
                                    kt * 32 + (lane >> 4) * 8);
        racc[nt] = __builtin_amdgcn_mfma_f32_16x16x32_bf16(a, b, racc[nt], 0, 0, 0);
      }
    }
    bar_lds();                      // all waves done reading bufA chunk kc
    if (kc == 0) {
#pragma unroll
      for (int it = 0; it < 8; ++it) {
        int idx = it * 256 + tid;
        int r = idx >> 6, k4 = idx & 63;
        int m = rowbase + r;
        int bt = m >> 4;
        float4 cx = *(const float4*)(ctx + (size_t)bt * 512 + 256 + k4 * 4);
        float4 dv = dd1[it];
        u32* p = (u32*)(bufA + r * 264 + k4 * 4);
        p[0] = (u32)f2bf(cx.x * dv.x) | ((u32)f2bf(cx.y * dv.y) << 16);
        p[1] = (u32)f2bf(cx.z * dv.z) | ((u32)f2bf(cx.w * dv.w) << 16);
      }
      bar_lds();
    }
  }
  // racc -> bufC[:, 64:128]
  {
    int mr = mbase + (lane >> 4) * 4;
#pragma unroll
    for (int nt = 0; nt < 2; ++nt) {
      int nl = nhalf * 32 + nt * 16 + (lane & 15);
      float bv = mlp_b[nl];
#pragma unroll
      for (int r = 0; r < 4; ++r)
        bufC[(mr + r) * 136 + 64 + nl] = f2bf(racc[nt][r] + bv);
    }
  }
  bar_lds();
  stage_mfma<8, 4, true>(wbf + O_LW1, lm_b1, bufC, 136, bufB, 264, 0, lane, msub, nhalf);
  bar_lds();
  stage_mfma<4, 8, true>(wbf + O_LW2, lm_b2, bufB, 264, bufA, 264, 0, lane, msub, nhalf);
  bar_lds();

  // fused lw3 (relu) + lw4 dot: in-register, shfl reduce, one LDS atomic
  {
    f32x4 acc[2];
    acc[0] = f32x4{0.f, 0.f, 0.f, 0.f};
    acc[1] = f32x4{0.f, 0.f, 0.f, 0.f};
#pragma unroll
    for (int kt = 0; kt < 4; ++kt) {
      short8 a = *(const short8*)(bufA + (mbase + (lane & 15)) * 264 + kt * 32 + (lane >> 4) * 8);
#pragma unroll
      for (int nt = 0; nt < 2; ++nt) {
        int n = nhalf * 32 + nt * 16 + (lane & 15);
        short8 b = *(const short8*)(wbf + O_LW3 + (size_t)n * 128 +
                                    kt * 32 + (lane >> 4) * 8);
        acc[nt] = __builtin_amdgcn_mfma_f32_16x16x32_bf16(a, b, acc[nt], 0, 0, 0);
      }
    }
    float psum[4] = {0.f, 0.f, 0.f, 0.f};
#pragma unroll
    for (int nt = 0; nt < 2; ++nt) {
      int nl = nhalf * 32 + nt * 16 + (lane & 15);
      float bv = lm_b3[nl], w4 = lm_W4[nl];
#pragma unroll
      for (int r = 0; r < 4; ++r) psum[r] += w4 * fmaxf(acc[nt][r] + bv, 0.f);
    }
#pragma unroll
    for (int off = 8; off >= 1; off >>= 1)
#pragma unroll
      for (int r = 0; r < 4; ++r) psum[r] += __shfl_xor(psum[r], off);
    if ((lane & 15) == 0) {
#pragma unroll
      for (int r = 0; r < 4; ++r)
        atomicAdd(&sred[mbase + (lane >> 4) * 4 + r], psum[r]);
    }
  }
  bar_lds();
  if (tid < 32) out[rowbase + tid] = sigf(sred[tid] + lm_b4[0]);
}

}  // namespace

extern "C" void kernel_launch(void* const* d_in, const int* in_sizes, int n_in,
                              void* d_out, int out_size, void* d_ws, size_t ws_size,
                              hipStream_t stream) {
  const float* x1   = (const float*)d_in[0];
  const float* d2v  = (const float*)d_in[1];
  const float* Wih  = (const float*)d_in[2];
  const float* Whh  = (const float*)d_in[3];
  const float* bih  = (const float*)d_in[4];
  const float* bhh  = (const float*)d_in[5];
  const float* aW1  = (const float*)d_in[6];
  const float* ab1  = (const float*)d_in[7];
  const float* aw2  = (const float*)d_in[8];
  const float* mlpW = (const float*)d_in[9];
  const float* mlpb = (const float*)d_in[10];
  const float* utab = (const float*)d_in[11];
  const float* atab = (const float*)d_in[12];
  const float* emW1 = (const float*)d_in[13];
  const float* emb1 = (const float*)d_in[14];
  const float* emW2 = (const float*)d_in[15];
  const float* emb2 = (const float*)d_in[16];
  const float* lmW1 = (const float*)d_in[17];
  const float* lmb1 = (const float*)d_in[18];
  const float* lmW2 = (const float*)d_in[19];
  const float* lmb2 = (const float*)d_in[20];
  const float* lmW3 = (const float*)d_in[21];
  const float* lmb3 = (const float*)d_in[22];
  const float* lmW4 = (const float*)d_in[23];
  const float* lmb4 = (const float*)d_in[24];
  const int* lens   = (const int*)d_in[27];
  const int* uids   = (const int*)d_in[28];
  const int* sids   = (const int*)d_in[29];
  float* out = (float*)d_out;

  float* ws = (float*)d_ws;
  // float-unit offsets
  signed char* WQ = (signed char*)ws;                  // 1 MB i8 [0, 262144)
  float* SC  = ws + 262144;                            // 8192
  u16* WBF = (u16*)(ws + 270336);                      // 2,490,368 u16
  float* XG  = ws + 1515520;                           // 16,777,216 f32
  float* R0  = ws + 18292736;                          // 4,194,304
  float* R1  = ws + 22487040;                          // 4,194,304
  float* CTX = ws + 18292736;                          // overlays R0 (R0 dead
                                                       // before k_ctx writes)

  k_prep<<<(N_WBF + 255) / 256, 256, 0, stream>>>(Wih, aW1, emW1, emW2, mlpW,
                                                  lmW1, lmW2, lmW3, WBF);
  k_prepw<<<4096, 256, 0, stream>>>(Whh, WQ);
  k_xg_mfma<<<dim3(256, 8), 256, 0, stream>>>(x1, WBF + O_WIH, bih, bhh, XG);
  k_lstm6<<<8, 1024, 0, stream>>>(XG, WQ, lens, R0, 0);
  k_xg_mfma<<<dim3(256, 8), 256, 0, stream>>>(R0, WBF + O_WIH + 1048576,
                                              bih + 2048, bhh + 2048, XG);
  k_lstm6<<<8, 1024, 0, stream>>>(XG, WQ, lens, R1, 1);
  k_attn<<<256, 256, 0, stream>>>(R1, WBF + O_AW1, ab1, aw2, SC);
  k_ctx<<<dim3(64, 4), 128, 0, stream>>>(SC, R1, lens, CTX);
  k_sample<<<4096, 256, 0, stream>>>(CTX, d2v, utab, atab, uids, sids, WBF,
                                     emb1, emb2, mlpb, lmb1, lmb2, lmb3,
                                     lmW4, lmb4, out);
}

// Round 14
// 1175.807 us; speedup vs baseline: 1.4013x; 1.4013x over previous
//
#include <hip/hip_runtime.h>
#include <cstddef>

namespace {

constexpr int T = 128;

typedef unsigned short u16;
typedef unsigned int u32;
typedef unsigned long long u64;
typedef __attribute__((ext_vector_type(8))) short short8;
typedef __attribute__((ext_vector_type(4))) float f32x4;
typedef __attribute__((ext_vector_type(4))) int i32x4;

__device__ __forceinline__ u16 f2bf(float x) {
  u32 u = __float_as_uint(x);
  u = (u + 0x7FFFu + ((u >> 16) & 1u)) >> 16;
  return (u16)u;
}
__device__ __forceinline__ float bf2f(u16 v) {
  return __uint_as_float(((u32)v) << 16);
}
// exp2/rcp-based activations: single v_exp_f32 / v_rcp_f32, branch-free.
__device__ __forceinline__ float sigf(float x) {
  return __builtin_amdgcn_rcpf(1.f + __builtin_amdgcn_exp2f(-1.44269504f * x));
}
__device__ __forceinline__ float tanh2(float x) {
  return 1.f - 2.f * __builtin_amdgcn_rcpf(1.f + __builtin_amdgcn_exp2f(2.88539008f * x));
}
// Barrier that drains ONLY LDS ops (lgkmcnt) — __syncthreads would also wait
// vmcnt(0), serializing on HBM store-acks that nothing after depends on.
__device__ __forceinline__ void bar_lds() {
  asm volatile("s_waitcnt lgkmcnt(0)\n\ts_barrier" ::: "memory");
}

// ---- WBF sub-offsets (ushort units) ----
constexpr int O_WIH = 0;            // 2*2048*512
constexpr int O_AW1 = 2097152;      // 512*512
constexpr int O_EM1 = 2359296;      // 128*128
constexpr int O_EM2 = 2375680;      // 64*128
constexpr int O_MLP = 2383872;      // 64*512
constexpr int O_LW1 = 2416640;      // 256*128
constexpr int O_LW2 = 2449408;      // 128*256
constexpr int O_LW3 = 2482176;      // 64*128
constexpr int N_WBF = 2490368;

// ---------------------------------------------------------------------------
// One-time fp32 -> bf16 weight conversion into workspace
// ---------------------------------------------------------------------------
__global__ __launch_bounds__(256)
void k_prep(const float* __restrict__ wih, const float* __restrict__ aw1,
            const float* __restrict__ e1, const float* __restrict__ e2,
            const float* __restrict__ mw, const float* __restrict__ l1,
            const float* __restrict__ l2, const float* __restrict__ l3,
            u16* __restrict__ wbf) {
  int i = blockIdx.x * 256 + threadIdx.x;
  if (i >= N_WBF) return;
  float v;
  if (i < O_AW1)      v = wih[i];
  else if (i < O_EM1) v = aw1[i - O_AW1];
  else if (i < O_EM2) v = e1[i - O_EM1];
  else if (i < O_MLP) v = e2[i - O_EM2];
  else if (i < O_LW1) v = mw[i - O_MLP];
  else if (i < O_LW2) v = l1[i - O_LW1];
  else if (i < O_LW3) v = l2[i - O_LW2];
  else                v = l3[i - O_LW3];
  wbf[i] = f2bf(v);
}

// ---------------------------------------------------------------------------
// Whh fp32 -> i8 (scale 1016 = 127/0.125; |w|max ~0.097, no clipping)
// ---------------------------------------------------------------------------
__global__ __launch_bounds__(256)
void k_prepw(const float* __restrict__ whh, signed char* __restrict__ wq) {
  int i = blockIdx.x * 256 + threadIdx.x;   // 1,048,576 total
  float v = whh[i] * 1016.f;
  v = fminf(fmaxf(v, -127.f), 127.f);
  wq[i] = (signed char)(int)rintf(v);
}

// ---------------------------------------------------------------------------
// xg = X @ Wih_l^T + bih + bhh   via MFMA.  grid (256 rowblk, 8 nchunk)
// ---------------------------------------------------------------------------
__global__ __launch_bounds__(256)
void k_xg_mfma(const float* __restrict__ X, const u16* __restrict__ Wbf,
               const float* __restrict__ bi, const float* __restrict__ bh,
               float* __restrict__ xg) {
  __shared__ __align__(16) u16 sx[32 * 520];
  int tid = threadIdx.x;
  int rowbase = blockIdx.x * 32;
  int nchunk = blockIdx.y;
  for (int idx = tid; idx < 4096; idx += 256) {
    int r = idx >> 7, k4 = idx & 127;
    float4 v = *(const float4*)(X + (size_t)(rowbase + r) * 512 + k4 * 4);
    u32* p = (u32*)(sx + r * 520 + k4 * 4);
    p[0] = (u32)f2bf(v.x) | ((u32)f2bf(v.y) << 16);
    p[1] = (u32)f2bf(v.z) | ((u32)f2bf(v.w) << 16);
  }
  __syncthreads();
  int w = tid >> 6, lane = tid & 63;
  int msub = w >> 1, nhalf = w & 1;
  int mbase = msub * 16;
  int nb0 = nchunk * 256 + nhalf * 128;
  f32x4 acc[8];
#pragma unroll
  for (int i = 0; i < 8; ++i) acc[i] = f32x4{0.f, 0.f, 0.f, 0.f};
  for (int kt = 0; kt < 16; ++kt) {
    short8 a = *(const short8*)(sx + (mbase + (lane & 15)) * 520 + kt * 32 + (lane >> 4) * 8);
#pragma unroll
    for (int nt = 0; nt < 8; ++nt) {
      short8 b = *(const short8*)(Wbf + (size_t)(nb0 + nt * 16 + (lane & 15)) * 512 +
                                  kt * 32 + (lane >> 4) * 8);
      acc[nt] = __builtin_amdgcn_mfma_f32_16x16x32_bf16(a, b, acc[nt], 0, 0, 0);
    }
  }
  int mr = mbase + (lane >> 4) * 4;
#pragma unroll
  for (int nt = 0; nt < 8; ++nt) {
    int n = nb0 + nt * 16 + (lane & 15);
    float bb = bi[n] + bh[n];
#pragma unroll
    for (int r = 0; r < 4; ++r)
      xg[(size_t)(rowbase + mr + r) * 2048 + n] = acc[nt][r] + bb;
  }
}

// ---------------------------------------------------------------------------
// MFMA MLP stage on a 32-row bf16 LDS tile (256-thread tile)
// ---------------------------------------------------------------------------
template <int NT, int KT, bool RELU>
__device__ __forceinline__ void stage_mfma(const u16* __restrict__ Wbf,
                                           const float* __restrict__ bias,
                                           const u16* A, int lda,
                                           u16* O, int ldo, int nofs,
                                           int lane, int msub, int nhalf) {
  f32x4 acc[NT];
#pragma unroll
  for (int i = 0; i < NT; ++i) acc[i] = f32x4{0.f, 0.f, 0.f, 0.f};
  int mbase = msub * 16;
  int nb0 = nhalf * (NT * 16);
#pragma unroll
  for (int kt = 0; kt < KT; ++kt) {
    short8 a = *(const short8*)(A + (mbase + (lane & 15)) * lda + kt * 32 + (lane >> 4) * 8);
#pragma unroll
    for (int nt = 0; nt < NT; ++nt) {
      short8 b = *(const short8*)(Wbf + (size_t)(nb0 + nt * 16 + (lane & 15)) * (KT * 32) +
                                  kt * 32 + (lane >> 4) * 8);
      acc[nt] = __builtin_amdgcn_mfma_f32_16x16x32_bf16(a, b, acc[nt], 0, 0, 0);
    }
  }
  int mr = mbase + (lane >> 4) * 4;
#pragma unroll
  for (int nt = 0; nt < NT; ++nt) {
    int nl = nb0 + nt * 16 + (lane & 15);
    float bv = bias[nl];
#pragma unroll
    for (int r = 0; r < 4; ++r) {
      float v = acc[nt][r] + bv;
      if (RELU) v = fmaxf(v, 0.f);
      O[(mr + r) * ldo + nofs + nl] = f2bf(v);
    }
  }
}

// ---------------------------------------------------------------------------
// MFMA LSTM (r11-proven 512-thr) + e-branch rider blocks.
// Blocks 0..7: [d:2][bg:4] batch-split LSTM, zero inter-block sync, Whh i8 in
// registers (128 VGPR), h in LDS, lgkm-only barrier per step.
// Blocks >=8 (layer-0 launch only): e-branch of the sample path — compute
// relu(em2(relu(em1(user*art)))) for 64 rows/block into EZ (bf16), using the
// otherwise-idle 248 CUs during the recurrence.
// ---------------------------------------------------------------------------
__global__ __launch_bounds__(512, 1)
void k_lstm6(const float* __restrict__ xg, const signed char* __restrict__ wq,
             const int* __restrict__ lens, float* __restrict__ out, int layer,
             const float* __restrict__ utab, const float* __restrict__ atab,
             const int* __restrict__ uids, const int* __restrict__ sids,
             const u16* __restrict__ wbf, const float* __restrict__ em_b1,
             const float* __restrict__ em_b2, u16* __restrict__ ez) {
  __shared__ __align__(16) signed char hq[2][16 * 272];
  __shared__ __align__(16) u16 ebufA[2 * 32 * 136];
  __shared__ __align__(16) u16 ebufB[2 * 32 * 136];
  const int tid = threadIdx.x;

  if (blockIdx.x >= 8) {
    // ---------------- e-branch rider (two independent 256-thr tiles) -------
    const int half = tid >> 8;
    const int t = tid & 255;
    const int lane = t & 63, wv = t >> 6;
    const int msub = wv >> 1, nhalf = wv & 1;
    const int rowbase = ((int)blockIdx.x - 8) * 64 + half * 32;
    u16* eA = ebufA + half * 4352;
    u16* eB = ebufB + half * 4352;
    // e0 = user_emb * art_emb -> eA
#pragma unroll
    for (int it = 0; it < 4; ++it) {
      int idx = it * 256 + t;
      int r = idx >> 5, k4 = idx & 31;
      int m = rowbase + r;
      int sid = sids[m];
      int uid = uids[m >> 11];
      float4 u = *(const float4*)(utab + (size_t)uid * 128 + k4 * 4);
      float4 a = *(const float4*)(atab + (size_t)sid * 128 + k4 * 4);
      u32* p = (u32*)(eA + r * 136 + k4 * 4);
      p[0] = (u32)f2bf(u.x * a.x) | ((u32)f2bf(u.y * a.y) << 16);
      p[1] = (u32)f2bf(u.z * a.z) | ((u32)f2bf(u.w * a.w) << 16);
    }
    bar_lds();
    stage_mfma<4, 4, true>(wbf + O_EM1, em_b1, eA, 136, eB, 136, 0, lane, msub, nhalf);
    bar_lds();
    // em2 -> EZ direct (global, bf16)
    {
      f32x4 acc[2];
      acc[0] = f32x4{0.f, 0.f, 0.f, 0.f};
      acc[1] = f32x4{0.f, 0.f, 0.f, 0.f};
#pragma unroll
      for (int kt = 0; kt < 4; ++kt) {
        short8 a = *(const short8*)(eB + (msub * 16 + (lane & 15)) * 136 +
                                    kt * 32 + (lane >> 4) * 8);
#pragma unroll
        for (int nt = 0; nt < 2; ++nt) {
          int n = nhalf * 32 + nt * 16 + (lane & 15);
          short8 b = *(const short8*)(wbf + O_EM2 + (size_t)n * 128 +
                                      kt * 32 + (lane >> 4) * 8);
          acc[nt] = __builtin_amdgcn_mfma_f32_16x16x32_bf16(a, b, acc[nt], 0, 0, 0);
        }
      }
      int mr = msub * 16 + (lane >> 4) * 4;
#pragma unroll
      for (int nt = 0; nt < 2; ++nt) {
        int n = nhalf * 32 + nt * 16 + (lane & 15);
        float bv = em_b2[n];
#pragma unroll
        for (int r = 0; r < 4; ++r)
          ez[(size_t)(rowbase + mr + r) * 64 + n] = f2bf(fmaxf(acc[nt][r] + bv, 0.f));
      }
    }
    return;
  }

  // ---------------- LSTM path (exact r11 structure) -------------------------
  const int d = blockIdx.x >> 2, bg = blockIdx.x & 3;
  const int jc = tid >> 6, l = tid & 63, ln = l & 15, lk = l >> 4;
  const int mb = bg * 16;

  i32x4 Bq[4][2][4];
  const signed char* wbase = wq + (size_t)(layer * 2 + d) * 262144;
#pragma unroll
  for (int g = 0; g < 4; ++g)
#pragma unroll
    for (int js = 0; js < 2; ++js)
#pragma unroll
      for (int kc = 0; kc < 4; ++kc) {
        int n = g * 256 + jc * 32 + js * 16 + ln;
        Bq[g][js][kc] = *(const i32x4*)(wbase + (size_t)n * 256 + kc * 64 + lk * 16);
      }

  int mlen[4];
#pragma unroll
  for (int r = 0; r < 4; ++r) mlen[r] = lens[mb + lk * 4 + r];

  float cst[2][4], hst[2][4];
#pragma unroll
  for (int js = 0; js < 2; ++js)
#pragma unroll
    for (int r = 0; r < 4; ++r) { cst[js][r] = 0.f; hst[js][r] = 0.f; }

  const float DEQ = 1.f / (1016.f * 127.f);

  for (int s = 0; s < 128; ++s) {
    const int t = d ? (127 - s) : s;

    float xv[4][2][4];
#pragma unroll
    for (int g = 0; g < 4; ++g)
#pragma unroll
      for (int js = 0; js < 2; ++js)
#pragma unroll
        for (int r = 0; r < 4; ++r)
          xv[g][js][r] = xg[((size_t)(mb + lk * 4 + r) * 128 + t) * 2048 +
                            d * 1024 + g * 256 + jc * 32 + js * 16 + ln];

    i32x4 acc[4][2];
#pragma unroll
    for (int g = 0; g < 4; ++g)
#pragma unroll
      for (int js = 0; js < 2; ++js) acc[g][js] = i32x4{0, 0, 0, 0};

    if (s > 0) {
      const signed char* hr = hq[(s & 1) ^ 1];
#pragma unroll
      for (int kc = 0; kc < 4; ++kc) {
        i32x4 a = *(const i32x4*)(hr + ln * 272 + kc * 64 + lk * 16);
#pragma unroll
        for (int g = 0; g < 4; ++g)
#pragma unroll
          for (int js = 0; js < 2; ++js)
            acc[g][js] = __builtin_amdgcn_mfma_i32_16x16x64_i8(a, Bq[g][js][kc],
                                                               acc[g][js], 0, 0, 0);
      }
    }

    signed char* hw = hq[s & 1];
#pragma unroll
    for (int js = 0; js < 2; ++js)
#pragma unroll
      for (int r = 0; r < 4; ++r) {
        float gi = (float)acc[0][js][r] * DEQ + xv[0][js][r];
        float gf = (float)acc[1][js][r] * DEQ + xv[1][js][r];
        float gg = (float)acc[2][js][r] * DEQ + xv[2][js][r];
        float go = (float)acc[3][js][r] * DEQ + xv[3][js][r];
        float c2 = sigf(gf) * cst[js][r] + sigf(gi) * tanh2(gg);
        float h2 = sigf(go) * tanh2(c2);
        const int m = lk * 4 + r;
        bool upd = t < mlen[r];
        cst[js][r] = upd ? c2 : cst[js][r];
        float hn = upd ? h2 : hst[js][r];
        hst[js][r] = hn;
        const int j = jc * 32 + js * 16 + ln;
        out[((size_t)(mb + m) * 128 + t) * 512 + d * 256 + j] = hn;
        hw[m * 272 + j] = (signed char)(int)rintf(hn * 127.f);
      }
    bar_lds();
  }
}

// ---------------------------------------------------------------------------
// attn scores via MFMA: sc[m] = w2 . tanh(W1 @ rnn[m] + b1)
// ---------------------------------------------------------------------------
__global__ __launch_bounds__(256)
void k_attn(const float* __restrict__ rnn, const u16* __restrict__ W1bf,
            const float* __restrict__ b1, const float* __restrict__ w2,
            float* __restrict__ sc) {
  __shared__ __align__(16) u16 sx[32 * 520];
  __shared__ float sred[32];
  int tid = threadIdx.x;
  int rowbase = blockIdx.x * 32;
  for (int idx = tid; idx < 4096; idx += 256) {
    int r = idx >> 7, k4 = idx & 127;
    float4 v = *(const float4*)(rnn + (size_t)(rowbase + r) * 512 + k4 * 4);
    u32* p = (u32*)(sx + r * 520 + k4 * 4);
    p[0] = (u32)f2bf(v.x) | ((u32)f2bf(v.y) << 16);
    p[1] = (u32)f2bf(v.z) | ((u32)f2bf(v.w) << 16);
  }
  if (tid < 32) sred[tid] = 0.f;
  __syncthreads();
  int w = tid >> 6, lane = tid & 63;
  int msub = w >> 1, nhalf = w & 1;
  int mbase = msub * 16;
  float psum[4] = {0.f, 0.f, 0.f, 0.f};
  for (int ng = 0; ng < 4; ++ng) {
    f32x4 acc[4];
#pragma unroll
    for (int i = 0; i < 4; ++i) acc[i] = f32x4{0.f, 0.f, 0.f, 0.f};
    for (int kt = 0; kt < 16; ++kt) {
      short8 a = *(const short8*)(sx + (mbase + (lane & 15)) * 520 + kt * 32 + (lane >> 4) * 8);
#pragma unroll
      for (int nt = 0; nt < 4; ++nt) {
        int nrow = nhalf * 256 + ng * 64 + nt * 16 + (lane & 15);
        short8 b = *(const short8*)(W1bf + (size_t)nrow * 512 + kt * 32 + (lane >> 4) * 8);
        acc[nt] = __builtin_amdgcn_mfma_f32_16x16x32_bf16(a, b, acc[nt], 0, 0, 0);
      }
    }
#pragma unroll
    for (int nt = 0; nt < 4; ++nt) {
      int n = nhalf * 256 + ng * 64 + nt * 16 + (lane & 15);
      float wn = w2[n], bn = b1[n];
#pragma unroll
      for (int r = 0; r < 4; ++r) psum[r] += wn * tanh2(acc[nt][r] + bn);
    }
  }
#pragma unroll
  for (int off = 8; off >= 1; off >>= 1)
#pragma unroll
    for (int r = 0; r < 4; ++r) psum[r] += __shfl_xor(psum[r], off);
  if ((lane & 15) == 0) {
#pragma unroll
    for (int r = 0; r < 4; ++r)
      atomicAdd(&sred[msub * 16 + (lane >> 4) * 4 + r], psum[r]);
  }
  __syncthreads();
  if (tid < 32) sc[rowbase + tid] = sred[tid];
}

// ---------------------------------------------------------------------------
// Causal softmax + weighted sum as prefix scan. grid (64 b, 4 hchunk) x 128.
// ---------------------------------------------------------------------------
__global__ __launch_bounds__(128)
void k_ctx(const float* __restrict__ sc, const float* __restrict__ rnn,
           const int* __restrict__ lens, float* __restrict__ ctx) {
  int b = blockIdx.x;
  int h = blockIdx.y * 128 + threadIdx.x;
  __shared__ float ex[T];
  ex[threadIdx.x] = expf(sc[b * T + threadIdx.x]);
  __syncthreads();
  int len = lens[b];
  float acc = 0.f, den = 0.f;
  for (int t = 0; t < T; ++t) {
    float wv = ex[t];
    den += wv;
    acc += wv * rnn[((size_t)b * T + t) * 512 + h];
    ctx[((size_t)b * T + t) * 512 + h] = (t < len) ? (acc / den) : 0.f;
  }
}

// ---------------------------------------------------------------------------
// Fused sample branch (post-EZ). 32 rows/block, 4096 blocks, 3 blk/CU.
// e-path read from EZ; r-branch + lm chain as r12 (register-first gathers).
// ---------------------------------------------------------------------------
__global__ __launch_bounds__(256)
void k_sample(const float* __restrict__ ctx, const float* __restrict__ d2v,
              const u16* __restrict__ ez,
              const u16* __restrict__ wbf, const float* __restrict__ mlp_b,
              const float* __restrict__ lm_b1, const float* __restrict__ lm_b2,
              const float* __restrict__ lm_b3,
              const float* __restrict__ lm_W4, const float* __restrict__ lm_b4,
              float* __restrict__ out) {
  __shared__ __align__(16) u16 bufA[32 * 264];
  __shared__ __align__(16) u16 bufB[32 * 264];
  __shared__ __align__(16) u16 bufC[32 * 136];
  __shared__ float sred[32];
  int tid = threadIdx.x, lane = tid & 63, w = tid >> 6;
  int msub = w >> 1, nhalf = w & 1;
  int mbase = msub * 16;
  int rowbase = blockIdx.x * 32;

  if (tid < 32) sred[tid] = 0.f;

  // EZ -> bufC[:, 0:64]
  for (int idx = tid; idx < 512; idx += 256) {
    int r = idx >> 4, q = idx & 15;
    *(u64*)(bufC + r * 136 + q * 4) =
        *(const u64*)(ez + (size_t)(rowbase + r) * 64 + q * 4);
  }

  // issue d2v gathers into registers
  float4 dd0[8], dd1[8];
#pragma unroll
  for (int it = 0; it < 8; ++it) {
    int idx = it * 256 + tid;
    int r = idx >> 6, k4 = idx & 63;
    int m = rowbase + r;
    dd0[it] = *(const float4*)(d2v + (size_t)m * 512 + k4 * 4);
  }
#pragma unroll
  for (int it = 0; it < 8; ++it) {
    int idx = it * 256 + tid;
    int r = idx >> 6, k4 = idx & 63;
    int m = rowbase + r;
    dd1[it] = *(const float4*)(d2v + (size_t)m * 512 + 256 + k4 * 4);
  }

  // r-input chunk0: ctx * d2v -> bufA
#pragma unroll
  for (int it = 0; it < 8; ++it) {
    int idx = it * 256 + tid;
    int r = idx >> 6, k4 = idx & 63;
    int m = rowbase + r;
    int bt = m >> 4;
    float4 cx = *(const float4*)(ctx + (size_t)bt * 512 + k4 * 4);
    float4 dv = dd0[it];
    u32* p = (u32*)(bufA + r * 264 + k4 * 4);
    p[0] = (u32)f2bf(cx.x * dv.x) | ((u32)f2bf(cx.y * dv.y) << 16);
    p[1] = (u32)f2bf(cx.z * dv.z) | ((u32)f2bf(cx.w * dv.w) << 16);
  }
  bar_lds();

  // r = (ctx*d2v) @ mlp_W^T : accumulate over 2 K-chunks of 256
  f32x4 racc[2];
  racc[0] = f32x4{0.f, 0.f, 0.f, 0.f};
  racc[1] = f32x4{0.f, 0.f, 0.f, 0.f};
  for (int kc = 0; kc < 2; ++kc) {
#pragma unroll
    for (int kt = 0; kt < 8; ++kt) {
      short8 a = *(const short8*)(bufA + (mbase + (lane & 15)) * 264 + kt * 32 + (lane >> 4) * 8);
#pragma unroll
      for (int nt = 0; nt < 2; ++nt) {
        int n = nhalf * 32 + nt * 16 + (lane & 15);
        short8 b = *(const short8*)(wbf + O_MLP + (size_t)n * 512 + kc * 256 +
                                    kt * 32 + (lane >> 4) * 8);
        racc[nt] = __builtin_amdgcn_mfma_f32_16x16x32_bf16(a, b, racc[nt], 0, 0, 0);
      }
    }
    bar_lds();                      // all waves done reading bufA chunk kc
    if (kc == 0) {
#pragma unroll
      for (int it = 0; it < 8; ++it) {
        int idx = it * 256 + tid;
        int r = idx >> 6, k4 = idx & 63;
        int m = rowbase + r;
        int bt = m >> 4;
        float4 cx = *(const float4*)(ctx + (size_t)bt * 512 + 256 + k4 * 4);
        float4 dv = dd1[it];
        u32* p = (u32*)(bufA + r * 264 + k4 * 4);
        p[0] = (u32)f2bf(cx.x * dv.x) | ((u32)f2bf(cx.y * dv.y) << 16);
        p[1] = (u32)f2bf(cx.z * dv.z) | ((u32)f2bf(cx.w * dv.w) << 16);
      }
      bar_lds();
    }
  }
  // racc -> bufC[:, 64:128]
  {
    int mr = mbase + (lane >> 4) * 4;
#pragma unroll
    for (int nt = 0; nt < 2; ++nt) {
      int nl = nhalf * 32 + nt * 16 + (lane & 15);
      float bv = mlp_b[nl];
#pragma unroll
      for (int r = 0; r < 4; ++r)
        bufC[(mr + r) * 136 + 64 + nl] = f2bf(racc[nt][r] + bv);
    }
  }
  bar_lds();
  stage_mfma<8, 4, true>(wbf + O_LW1, lm_b1, bufC, 136, bufB, 264, 0, lane, msub, nhalf);
  bar_lds();
  stage_mfma<4, 8, true>(wbf + O_LW2, lm_b2, bufB, 264, bufA, 264, 0, lane, msub, nhalf);
  bar_lds();

  // fused lw3 (relu) + lw4 dot: in-register, shfl reduce, one LDS atomic
  {
    f32x4 acc[2];
    acc[0] = f32x4{0.f, 0.f, 0.f, 0.f};
    acc[1] = f32x4{0.f, 0.f, 0.f, 0.f};
#pragma unroll
    for (int kt = 0; kt < 4; ++kt) {
      short8 a = *(const short8*)(bufA + (mbase + (lane & 15)) * 264 + kt * 32 + (lane >> 4) * 8);
#pragma unroll
      for (int nt = 0; nt < 2; ++nt) {
        int n = nhalf * 32 + nt * 16 + (lane & 15);
        short8 b = *(const short8*)(wbf + O_LW3 + (size_t)n * 128 +
                                    kt * 32 + (lane >> 4) * 8);
        acc[nt] = __builtin_amdgcn_mfma_f32_16x16x32_bf16(a, b, acc[nt], 0, 0, 0);
      }
    }
    float psum[4] = {0.f, 0.f, 0.f, 0.f};
#pragma unroll
    for (int nt = 0; nt < 2; ++nt) {
      int nl = nhalf * 32 + nt * 16 + (lane & 15);
      float bv = lm_b3[nl], w4 = lm_W4[nl];
#pragma unroll
      for (int r = 0; r < 4; ++r) psum[r] += w4 * fmaxf(acc[nt][r] + bv, 0.f);
    }
#pragma unroll
    for (int off = 8; off >= 1; off >>= 1)
#pragma unroll
      for (int r = 0; r < 4; ++r) psum[r] += __shfl_xor(psum[r], off);
    if ((lane & 15) == 0) {
#pragma unroll
      for (int r = 0; r < 4; ++r)
        atomicAdd(&sred[mbase + (lane >> 4) * 4 + r], psum[r]);
    }
  }
  bar_lds();
  if (tid < 32) out[rowbase + tid] = sigf(sred[tid] + lm_b4[0]);
}

}  // namespace

extern "C" void kernel_launch(void* const* d_in, const int* in_sizes, int n_in,
                              void* d_out, int out_size, void* d_ws, size_t ws_size,
                              hipStream_t stream) {
  const float* x1   = (const float*)d_in[0];
  const float* d2v  = (const float*)d_in[1];
  const float* Wih  = (const float*)d_in[2];
  const float* Whh  = (const float*)d_in[3];
  const float* bih  = (const float*)d_in[4];
  const float* bhh  = (const float*)d_in[5];
  const float* aW1  = (const float*)d_in[6];
  const float* ab1  = (const float*)d_in[7];
  const float* aw2  = (const float*)d_in[8];
  const float* mlpW = (const float*)d_in[9];
  const float* mlpb = (const float*)d_in[10];
  const float* utab = (const float*)d_in[11];
  const float* atab = (const float*)d_in[12];
  const float* emW1 = (const float*)d_in[13];
  const float* emb1 = (const float*)d_in[14];
  const float* emW2 = (const float*)d_in[15];
  const float* emb2 = (const float*)d_in[16];
  const float* lmW1 = (const float*)d_in[17];
  const float* lmb1 = (const float*)d_in[18];
  const float* lmW2 = (const float*)d_in[19];
  const float* lmb2 = (const float*)d_in[20];
  const float* lmW3 = (const float*)d_in[21];
  const float* lmb3 = (const float*)d_in[22];
  const float* lmW4 = (const float*)d_in[23];
  const float* lmb4 = (const float*)d_in[24];
  const int* lens   = (const int*)d_in[27];
  const int* uids   = (const int*)d_in[28];
  const int* sids   = (const int*)d_in[29];
  float* out = (float*)d_out;

  float* ws = (float*)d_ws;
  // float-unit offsets
  signed char* WQ = (signed char*)ws;                  // 1 MB i8 [0, 262144)
  float* SC  = ws + 262144;                            // 8192
  u16* WBF = (u16*)(ws + 270336);                      // 2,490,368 u16
  float* XG  = ws + 1515520;                           // 16,777,216 f32
  float* R0  = ws + 18292736;                          // 4,194,304
  float* R1  = ws + 22487040;                          // 4,194,304
  u16* EZ  = (u16*)(ws + 26681344);                    // 8,388,608 u16
  float* CTX = ws + 18292736;                          // overlays R0 (R0 dead
                                                       // before k_ctx writes)

  k_prep<<<(N_WBF + 255) / 256, 256, 0, stream>>>(Wih, aW1, emW1, emW2, mlpW,
                                                  lmW1, lmW2, lmW3, WBF);
  k_prepw<<<4096, 256, 0, stream>>>(Whh, WQ);
  k_xg_mfma<<<dim3(256, 8), 256, 0, stream>>>(x1, WBF + O_WIH, bih, bhh, XG);
  // layer-0 LSTM + e-branch riders on the idle CUs
  k_lstm6<<<8 + 2048, 512, 0, stream>>>(XG, WQ, lens, R0, 0,
                                        utab, atab, uids, sids,
                                        WBF, emb1, emb2, EZ);
  k_xg_mfma<<<dim3(256, 8), 256, 0, stream>>>(R0, WBF + O_WIH + 1048576,
                                              bih + 2048, bhh + 2048, XG);
  k_lstm6<<<8, 512, 0, stream>>>(XG, WQ, lens, R1, 1,
                                 utab, atab, uids, sids,
                                 WBF, emb1, emb2, EZ);
  k_attn<<<256, 256, 0, stream>>>(R1, WBF + O_AW1, ab1, aw2, SC);
  k_ctx<<<dim3(64, 4), 128, 0, stream>>>(SC, R1, lens, CTX);
  k_sample<<<4096, 256, 0, stream>>>(CTX, d2v, EZ, WBF, mlpb,
                                     lmb1, lmb2, lmb3, lmW4, lmb4, out);
}